// Round 5
// baseline (161.707 us; speedup 1.0000x reference)
//
#include <hip/hip_runtime.h>
#include <hip/hip_bf16.h>

#define NB 4
#define NC 128
#define NH 128
#define NW 240
#define NE 64
#define NK 9
#define PLANE (NH*NW)
#define CHW (NC*PLANE)
#define XS 244               // xs row stride in ushort
#define EMB_ELEMS (NB*NH*NW*NE)          // 7,864,320 bf16 per tensor

typedef __attribute__((ext_vector_type(8))) short short8;
typedef __attribute__((ext_vector_type(4))) float f32x4;

__device__ __forceinline__ unsigned pk2bf(float x, float y){
  __hip_bfloat162 h = __float22bfloat162_rn(make_float2(x, y));
  return *(unsigned*)&h;
}
__device__ __forceinline__ unsigned short f2bf(float f){
  unsigned u = __float_as_uint(f);
  u += 0x7fffu + ((u>>16)&1u);
  return (unsigned short)(u>>16);
}
__device__ __forceinline__ float bfl(unsigned v){ return __uint_as_float(v<<16); }
__device__ __forceinline__ float bfh(unsigned v){ return __uint_as_float(v & 0xffff0000u); }

// ================= K1: embed + normalize. one block per (tensor,b,h) =========
// LDS: xs 128x244 bf16 + phis 64x136 bf16 = 79,872 B -> 2 blocks/CU.
__global__ __launch_bounds__(512, 4)
void embed_kernel(const float* __restrict__ xL,
                  const float* __restrict__ xR,
                  const float* __restrict__ phig,
                  unsigned short* __restrict__ emb)   // [t][b][h][w][e] bf16
{
  __shared__ __attribute__((aligned(16))) unsigned short xs[NC*XS];
  __shared__ __attribute__((aligned(16))) unsigned short phis[NE*136];

  const int tid  = threadIdx.x;
  const int lane = tid & 63;
  const int wv   = tid >> 6;
  const int t    = blockIdx.x >> 9;
  const int bh   = blockIdx.x & 511;
  const float* __restrict__ src = t ? xR : xL;
  const size_t base = (size_t)(bh >> 7)*CHW + (size_t)(bh & 127)*NW;
  unsigned short* __restrict__ outp = emb + (size_t)t*EMB_ELEMS + (size_t)bh*(NW*NE);

  // stage phi: 2048 float4, coalesced
  #pragma unroll
  for (int i = 0; i < 4; ++i) {
    int idx = i*512 + tid;
    int e = idx >> 5, q = idx & 31;
    float4 v = *(const float4*)(phig + e*128 + 4*q);
    uint2 pk; pk.x = pk2bf(v.x, v.y); pk.y = pk2bf(v.z, v.w);
    *(uint2*)&phis[e*136 + 4*q] = pk;
  }
  // stage x row: 7680 float4, coalesced along W
  #pragma unroll
  for (int i = 0; i < 15; ++i) {
    int idx = i*512 + tid;
    int c = idx / 60, s = idx - 60*c;
    float4 v = *(const float4*)(src + base + (size_t)c*PLANE + 4*s);
    uint2 pk; pk.x = pk2bf(v.x, v.y); pk.y = pk2bf(v.z, v.w);
    *(uint2*)&xs[c*XS + 4*s] = pk;
  }
  __syncthreads();

  const int mrow = lane & 15;
  const int kg   = lane >> 4;

  #pragma unroll
  for (int it = 0; it < 2; ++it) {
    const int nt = wv*2 + it;
    if (nt >= 15) continue;
    f32x4 acc[4];
    #pragma unroll
    for (int mt = 0; mt < 4; ++mt) acc[mt] = (f32x4){0.f,0.f,0.f,0.f};
    const int col = 16*nt + mrow;
    #pragma unroll
    for (int ks = 0; ks < 4; ++ks) {
      const int r0 = 32*ks + 8*kg;
      short8 bfv;
      #pragma unroll
      for (int j = 0; j < 8; ++j)
        bfv[j] = (short)xs[(r0 + j)*XS + col];
      #pragma unroll
      for (int mt = 0; mt < 4; ++mt) {
        short8 af = *(const short8*)&phis[(16*mt + mrow)*136 + 32*ks + 8*kg];
        acc[mt] = __builtin_amdgcn_mfma_f32_16x16x32_bf16(af, bfv, acc[mt], 0, 0, 0);
      }
    }
    float ss = 0.f;
    #pragma unroll
    for (int mt = 0; mt < 4; ++mt)
      #pragma unroll
      for (int r = 0; r < 4; ++r)
        ss += acc[mt][r]*acc[mt][r];
    ss += __shfl_xor(ss, 16, 64);
    ss += __shfl_xor(ss, 32, 64);
    float inv = 1.f/(sqrtf(ss) + 1e-6f);
    const int n = 16*nt + mrow;
    #pragma unroll
    for (int mt = 0; mt < 4; ++mt) {
      int e0 = 16*mt + 4*kg;
      ushort4 pk;
      pk.x = f2bf(acc[mt][0]*inv);
      pk.y = f2bf(acc[mt][1]*inv);
      pk.z = f2bf(acc[mt][2]*inv);
      pk.w = f2bf(acc[mt][3]*inv);
      *(ushort4*)&outp[n*NE + e0] = pk;
    }
  }
}

// ================= K2: banded cost volume. one block per (b,h) ===============
// LDS: FLb + FRb 240x64 bf16 XOR-swizzled = 61,440 B -> 2 blocks/CU.
__global__ __launch_bounds__(256, 4)
void cost_kernel(const unsigned short* __restrict__ emb,
                 const float* __restrict__ d0g,
                 float* __restrict__ outg)
{
  __shared__ __attribute__((aligned(16))) unsigned short FLb[NW*64];
  __shared__ __attribute__((aligned(16))) unsigned short FRb[NW*64];

  const int tid = threadIdx.x;
  const int bh  = blockIdx.x;
  const int b   = bh >> 7;
  const int h   = bh & 127;

  float d0v = 0.f;
  if (tid < NW) d0v = d0g[bh*NW + tid];

  const unsigned short* __restrict__ FLg = emb + (size_t)bh*(NW*NE);
  const unsigned short* __restrict__ FRg = emb + (size_t)EMB_ELEMS + (size_t)bh*(NW*NE);

  // stage both rows, coalesced read -> swizzled LDS write (1920 uint4 each)
  #pragma unroll
  for (int i = 0; i < 8; ++i) {       // FL: 1920/256 = 7.5 -> 8 iters, last partial
    int idx = i*256 + tid;
    if (idx < 1920) {
      uint4 v = *(const uint4*)(FLg + idx*8);
      int p = idx >> 3, c = idx & 7;
      *(uint4*)&FLb[p*64 + ((c ^ (p&7))<<3)] = v;
    }
  }
  #pragma unroll
  for (int i = 0; i < 8; ++i) {
    int idx = i*256 + tid;
    if (idx < 1920) {
      uint4 v = *(const uint4*)(FRg + idx*8);
      int p = idx >> 3, c = idx & 7;
      *(uint4*)&FRb[p*64 + ((c ^ (p&7))<<3)] = v;
    }
  }
  __syncthreads();

  if (tid < NW) {
    const int p = tid;
    float xf  = (float)p - d0v;
    float x0  = floorf(xf);
    float wfr = xf - x0;
    int jb = (int)x0 - 4;

    float fl[64];
    #pragma unroll
    for (int c = 0; c < 8; ++c) {
      uint4 raw = *(const uint4*)&FLb[p*64 + ((c ^ (p&7))<<3)];
      fl[8*c+0]=bfl(raw.x); fl[8*c+1]=bfh(raw.x);
      fl[8*c+2]=bfl(raw.y); fl[8*c+3]=bfh(raw.y);
      fl[8*c+4]=bfl(raw.z); fl[8*c+5]=bfh(raw.z);
      fl[8*c+6]=bfl(raw.w); fl[8*c+7]=bfh(raw.w);
    }

    float D[10];
    #pragma unroll
    for (int t = 0; t < 10; ++t) {
      int j = jb + t;
      j = j < 0 ? 0 : (j > NW-1 ? NW-1 : j);
      float s = 0.f;
      #pragma unroll
      for (int c = 0; c < 8; ++c) {
        uint4 raw = *(const uint4*)&FRb[j*64 + ((c ^ (j&7))<<3)];
        s += fl[8*c+0]*bfl(raw.x) + fl[8*c+1]*bfh(raw.x)
           + fl[8*c+2]*bfl(raw.y) + fl[8*c+3]*bfh(raw.y)
           + fl[8*c+4]*bfl(raw.z) + fl[8*c+5]*bfh(raw.z)
           + fl[8*c+6]*bfl(raw.w) + fl[8*c+7]*bfh(raw.w);
      }
      D[t] = s;
    }

    size_t ob = (size_t)(b*NK)*PLANE + (size_t)h*NW + p;
    #pragma unroll
    for (int k = 0; k < NK; ++k) {
      int t0 = 8 - k;
      float cv = (1.f - wfr)*D[t0] + wfr*D[t0+1];
      outg[ob + (size_t)k*PLANE] = cv;
    }
  }
}

// ================= fallback: fused single-kernel (R4 version) ================
__global__ __launch_bounds__(1024, 4)
void corr_fused(const float* __restrict__ xL,
                const float* __restrict__ xR,
                const float* __restrict__ d0g,
                const float* __restrict__ phig,
                float* __restrict__ outg)
{
  __shared__ __attribute__((aligned(16))) unsigned short xs[NC*XS];
  __shared__ __attribute__((aligned(16))) unsigned short phis[NE*136];
  __shared__ __attribute__((aligned(16))) unsigned short FLb[NW*64];
  __shared__ __attribute__((aligned(16))) unsigned short FRb[NW*64];

  const int tid  = threadIdx.x;
  const int lane = tid & 63;
  const int wv   = tid >> 6;
  const int b    = blockIdx.x >> 7;
  const int h    = blockIdx.x & 127;
  const size_t base = (size_t)b*CHW + (size_t)h*NW;

  float d0v = 0.f;
  if (tid < NW) d0v = d0g[(b*NH + h)*NW + tid];

  #pragma unroll
  for (int i = 0; i < 2; ++i) {
    int idx = i*1024 + tid;
    int e = idx >> 5, q = idx & 31;
    float4 v = *(const float4*)(phig + e*128 + 4*q);
    uint2 pk; pk.x = pk2bf(v.x, v.y); pk.y = pk2bf(v.z, v.w);
    *(uint2*)&phis[e*136 + 4*q] = pk;
  }
  #pragma unroll
  for (int i = 0; i < 8; ++i) {
    int tau = i*1024 + tid;
    int c = tau >> 6, s = tau & 63;
    if (s < 60) {
      float4 v = *(const float4*)(xL + base + (size_t)c*PLANE + 4*s);
      uint2 pk; pk.x = pk2bf(v.x, v.y); pk.y = pk2bf(v.z, v.w);
      *(uint2*)&xs[c*XS + 4*s] = pk;
    }
  }
  __syncthreads();

  const int mrow = lane & 15;
  const int kg   = lane >> 4;
  const int nt   = wv;

  auto gemm_norm = [&](unsigned short* dst) {
    f32x4 acc[4];
    #pragma unroll
    for (int mt = 0; mt < 4; ++mt) acc[mt] = (f32x4){0.f,0.f,0.f,0.f};
    if (nt < 15) {
      const int col = 16*nt + mrow;
      #pragma unroll
      for (int ks = 0; ks < 4; ++ks) {
        const int r0 = 32*ks + 8*kg;
        short8 bfv;
        #pragma unroll
        for (int j = 0; j < 8; ++j)
          bfv[j] = (short)xs[(r0 + j)*XS + col];
        #pragma unroll
        for (int mt = 0; mt < 4; ++mt) {
          short8 af = *(const short8*)&phis[(16*mt + mrow)*136 + 32*ks + 8*kg];
          acc[mt] = __builtin_amdgcn_mfma_f32_16x16x32_bf16(af, bfv, acc[mt], 0, 0, 0);
        }
      }
      float ss = 0.f;
      #pragma unroll
      for (int mt = 0; mt < 4; ++mt)
        #pragma unroll
        for (int r = 0; r < 4; ++r)
          ss += acc[mt][r]*acc[mt][r];
      ss += __shfl_xor(ss, 16, 64);
      ss += __shfl_xor(ss, 32, 64);
      float inv = 1.f/(sqrtf(ss) + 1e-6f);
      int n = 16*nt + mrow;
      #pragma unroll
      for (int mt = 0; mt < 4; ++mt) {
        int e0 = 16*mt + 4*kg;
        ushort4 pk;
        pk.x = f2bf(acc[mt][0]*inv);
        pk.y = f2bf(acc[mt][1]*inv);
        pk.z = f2bf(acc[mt][2]*inv);
        pk.w = f2bf(acc[mt][3]*inv);
        int pos = n*64 + (((e0>>3) ^ (n&7))<<3) + (e0&7);
        *(ushort4*)&dst[pos] = pk;
      }
    }
  };

  gemm_norm(FLb);
  __syncthreads();
  #pragma unroll
  for (int i = 0; i < 8; ++i) {
    int tau = i*1024 + tid;
    int c = tau >> 6, s = tau & 63;
    if (s < 60) {
      float4 v = *(const float4*)(xR + base + (size_t)c*PLANE + 4*s);
      uint2 pk; pk.x = pk2bf(v.x, v.y); pk.y = pk2bf(v.z, v.w);
      *(uint2*)&xs[c*XS + 4*s] = pk;
    }
  }
  __syncthreads();
  gemm_norm(FRb);
  __syncthreads();

  if (tid < NW) {
    const int p = tid;
    float xf  = (float)p - d0v;
    float x0  = floorf(xf);
    float wfr = xf - x0;
    int jb = (int)x0 - 4;
    float fl[64];
    #pragma unroll
    for (int c = 0; c < 8; ++c) {
      uint4 raw = *(const uint4*)&FLb[p*64 + ((c ^ (p&7))<<3)];
      fl[8*c+0]=bfl(raw.x); fl[8*c+1]=bfh(raw.x);
      fl[8*c+2]=bfl(raw.y); fl[8*c+3]=bfh(raw.y);
      fl[8*c+4]=bfl(raw.z); fl[8*c+5]=bfh(raw.z);
      fl[8*c+6]=bfl(raw.w); fl[8*c+7]=bfh(raw.w);
    }
    float D[10];
    #pragma unroll
    for (int t = 0; t < 10; ++t) {
      int j = jb + t;
      j = j < 0 ? 0 : (j > NW-1 ? NW-1 : j);
      float s = 0.f;
      #pragma unroll
      for (int c = 0; c < 8; ++c) {
        uint4 raw = *(const uint4*)&FRb[j*64 + ((c ^ (j&7))<<3)];
        s += fl[8*c+0]*bfl(raw.x) + fl[8*c+1]*bfh(raw.x)
           + fl[8*c+2]*bfl(raw.y) + fl[8*c+3]*bfh(raw.y)
           + fl[8*c+4]*bfl(raw.z) + fl[8*c+5]*bfh(raw.z)
           + fl[8*c+6]*bfl(raw.w) + fl[8*c+7]*bfh(raw.w);
      }
      D[t] = s;
    }
    size_t ob = (size_t)(b*NK)*PLANE + (size_t)h*NW + p;
    #pragma unroll
    for (int k = 0; k < NK; ++k) {
      int t0 = 8 - k;
      float cv = (1.f - wfr)*D[t0] + wfr*D[t0+1];
      outg[ob + (size_t)k*PLANE] = cv;
    }
  }
}

extern "C" void kernel_launch(void* const* d_in, const int* in_sizes, int n_in,
                              void* d_out, int out_size, void* d_ws, size_t ws_size,
                              hipStream_t stream) {
  const float* xL   = (const float*)d_in[0];
  const float* xR   = (const float*)d_in[1];
  const float* d0g  = (const float*)d_in[2];
  const float* phig = (const float*)d_in[3];
  float* outg = (float*)d_out;

  const size_t need = (size_t)2 * EMB_ELEMS * sizeof(unsigned short);  // 31.5 MB
  if (ws_size >= need) {
    unsigned short* emb = (unsigned short*)d_ws;
    embed_kernel<<<dim3(2*NB*NH), dim3(512), 0, stream>>>(xL, xR, phig, emb);
    cost_kernel<<<dim3(NB*NH), dim3(256), 0, stream>>>(emb, d0g, outg);
  } else {
    corr_fused<<<dim3(NB*NH), dim3(1024), 0, stream>>>(xL, xR, d0g, phig, outg);
  }
}